// Round 3
// baseline (471.803 us; speedup 1.0000x reference)
//
#include <hip/hip_runtime.h>
#include <stdint.h>

#define N_NODES 100000
#define N_EDGES 1600000
#define NBLK_SCAN 391   // ceil(N_NODES/256)

typedef __attribute__((ext_vector_type(8))) short short8;
typedef __attribute__((ext_vector_type(4))) float float4v;

__device__ __forceinline__ unsigned short f32_to_bf16(float f) {
  uint32_t u = __float_as_uint(f);
  u += 0x7fffu + ((u >> 16) & 1u);   // RNE
  return (unsigned short)(u >> 16);
}
__device__ __forceinline__ float bf16_to_f32(unsigned short h) {
  return __uint_as_float(((uint32_t)h) << 16);
}

// ---------------------------------------------------------------------------
// K_zero: deg=0, scan tilepack=0, ticket=0  (ws is poisoned 0xAA every call)
// ---------------------------------------------------------------------------
__global__ __launch_bounds__(256) void k_zero(int* __restrict__ deg,
                                              unsigned long long* __restrict__ tilepack,
                                              int* __restrict__ tilectr) {
  int i = blockIdx.x * 256 + threadIdx.x;
  if (i < N_NODES) deg[i] = 0;
  if (i < NBLK_SCAN) tilepack[i] = 0ull;
  if (i == 0) *tilectr = 0;
}

// ---------------------------------------------------------------------------
// K_B (12500 blocks): fuses
//   - k0: out = x@root_w + bias; r_dot = (x@root_w).att_w[:32]   (all blocks)
//   - khist: deg histogram of edge targets                        (blocks<6250)
//   - kw: weight fp32 -> bf16 pre-swizzled to MFMA B-frag order   (blocks<100)
// ---------------------------------------------------------------------------
__global__ __launch_bounds__(256) void k_B(
    const float* __restrict__ x, const float* __restrict__ root_w,
    const float* __restrict__ att_w, const float* __restrict__ bias,
    const int* __restrict__ ei, const float* __restrict__ weight,
    float* __restrict__ out, float* __restrict__ r_dot,
    int* __restrict__ deg, unsigned short* __restrict__ wbf) {
  __shared__ float rw[32 * 32];
  __shared__ float xs[8 * 32];
  __shared__ float a1[32];
  __shared__ float bs[32];
  int tid = threadIdx.x;
  int b = blockIdx.x;

  if (b < 6250) {                       // histogram part
    int e = b * 256 + tid;              // exactly covers 1.6M edges
    atomicAdd(&deg[ei[e]], 1);
  }
  if (b < 100) {                        // weight swizzle part
    int e = b * 256 + tid;              // covers 25600
    int km = e >> 10;
    int rem = e & 1023;
    int kk = rem >> 5;
    int fo = rem & 31;
    int t = km * 2 + (fo >> 4);
    int c = fo & 15;
    int q = kk >> 3, j = kk & 7;
    wbf[((t * 4 + q) * 16 + c) * 8 + j] = f32_to_bf16(weight[e]);
  }

  int n0 = b * 8;
  for (int i = tid; i < 1024; i += 256) rw[i] = root_w[i];
  if (tid < 32) { a1[tid] = att_w[tid]; bs[tid] = bias[tid]; }
  int nl = tid >> 5, f = tid & 31;
  int n = n0 + nl;
  xs[tid] = (n < N_NODES) ? x[n * 32 + f] : 0.f;
  __syncthreads();
  float acc = 0.f;
#pragma unroll
  for (int kk = 0; kk < 32; kk++) acc += xs[nl * 32 + kk] * rw[kk * 32 + f];
  if (n < N_NODES) out[n * 32 + f] = acc + bs[f];
  float v = acc * a1[f];
#pragma unroll
  for (int m = 16; m >= 1; m >>= 1) v += __shfl_xor(v, m, 32);
  if (f == 0 && n < N_NODES) r_dot[n] = v;
}

// ---------------------------------------------------------------------------
// K_scan: single-kernel chained scan (decoupled lookback). 391 tiles x 256.
// tilepack[t] = flag(hi32: 0=empty,1=agg,2=incl-prefix) | value(lo32).
// Writes exclusive offsets to offs and cursor; offs[N_NODES]=N_EDGES.
// ---------------------------------------------------------------------------
__global__ __launch_bounds__(256) void k_scan(
    const int* __restrict__ deg, int* __restrict__ offs, int* __restrict__ cursor,
    int* __restrict__ tilectr, unsigned long long* __restrict__ tilepack) {
  __shared__ int s[256];
  __shared__ int sh_tile;
  __shared__ int sh_excl;
  int tid = threadIdx.x;
  if (tid == 0) sh_tile = atomicAdd(tilectr, 1);
  __syncthreads();
  int tile = sh_tile;
  int i = tile * 256 + tid;
  int v = (i < N_NODES) ? deg[i] : 0;
  s[tid] = v;
  __syncthreads();
  for (int d = 1; d < 256; d <<= 1) {
    int t = (tid >= d) ? s[tid - d] : 0;
    __syncthreads();
    s[tid] += t;
    __syncthreads();
  }
  int incl = s[tid];
  int agg = s[255];
  if (tid == 0) {
    if (tile == 0) {
      __hip_atomic_store(&tilepack[0], (2ull << 32) | (unsigned int)agg,
                         __ATOMIC_RELEASE, __HIP_MEMORY_SCOPE_AGENT);
      sh_excl = 0;
    } else {
      __hip_atomic_store(&tilepack[tile], (1ull << 32) | (unsigned int)agg,
                         __ATOMIC_RELEASE, __HIP_MEMORY_SCOPE_AGENT);
      int excl = 0;
      int t = tile - 1;
      while (true) {
        unsigned long long pk;
        do {
          pk = __hip_atomic_load(&tilepack[t], __ATOMIC_ACQUIRE, __HIP_MEMORY_SCOPE_AGENT);
        } while ((pk >> 32) == 0);
        excl += (int)(unsigned int)pk;
        if ((pk >> 32) == 2) break;
        t--;
      }
      __hip_atomic_store(&tilepack[tile], (2ull << 32) | (unsigned int)(excl + agg),
                         __ATOMIC_RELEASE, __HIP_MEMORY_SCOPE_AGENT);
      sh_excl = excl;
    }
  }
  __syncthreads();
  if (i < N_NODES) {
    int e = sh_excl + incl - v;
    offs[i] = e;
    cursor[i] = e;
  }
  if (i == N_NODES - 1) offs[N_NODES] = N_EDGES;
}

// ---------------------------------------------------------------------------
// K_C (12500 blocks): fuses
//   - blocks [0,6250): scatter edges into CSR order as 8B packets:
//       col(17b) | w0..w3(4x5b) | fr0,fr1(2x13b quantized)
//   - blocks [6250,12500): k1: xw[n][km*32+fo] = (x @ W_km)[n][fo] bf16 via
//       MFMA 16x16x32, LDS-staged, coalesced uint4 store. 16 nodes/block.
// ---------------------------------------------------------------------------
__global__ __launch_bounds__(256) void k_C(
    const int* __restrict__ ei, const float* __restrict__ pseudo,
    int* __restrict__ cursor, uint2* __restrict__ epack,
    const float* __restrict__ x, const unsigned short* __restrict__ wbf,
    unsigned short* __restrict__ xw) {
  __shared__ __align__(16) unsigned short ot[16 * 800];
  int tid = threadIdx.x;
  int b = blockIdx.x;

  if (b < 6250) {  // ---- scatter ----
    int e = b * 256 + tid;              // exactly 1.6M
    int r = ei[e];
    int c = ei[N_EDGES + e];
    int pos = atomicAdd(&cursor[r], 1);
    float p0 = pseudo[2 * e] * 4.f;
    float p1 = pseudo[2 * e + 1] * 4.f;
    float fl0 = floorf(p0), fl1 = floorf(p1);
    float fr0 = p0 - fl0, fr1 = p1 - fl1;
    int i0 = (int)fl0, i1 = (int)fl1;
    int a0 = min(i0, 4), a0p = min(i0 + 1, 4);
    int a1 = 5 * min(i1, 4), a1p = 5 * min(i1 + 1, 4);
    unsigned long long w0 = (unsigned long long)(a0 + a1);
    unsigned long long w1 = (unsigned long long)(a0p + a1);
    unsigned long long w2 = (unsigned long long)(a0 + a1p);
    unsigned long long w3 = (unsigned long long)(a0p + a1p);
    unsigned long long q0 = (unsigned long long)__float2uint_rn(fr0 * 8191.f);
    unsigned long long q1 = (unsigned long long)__float2uint_rn(fr1 * 8191.f);
    unsigned long long v = (unsigned long long)(unsigned int)c |
                           (w0 << 17) | (w1 << 22) | (w2 << 27) | (w3 << 32) |
                           (q0 << 37) | (q1 << 50);
    uint2 pk;
    pk.x = (unsigned int)v;
    pk.y = (unsigned int)(v >> 32);
    epack[pos] = pk;
    return;
  }

  // ---- k1: MFMA xw tile ----
  int wave = tid >> 6, lane = tid & 63;
  int quad = lane >> 4, c16 = lane & 15;
  int n0 = (b - 6250) * 16;
  const float* xp = x + (size_t)(n0 + c16) * 32 + quad * 8;
  float4 a0 = *reinterpret_cast<const float4*>(xp);
  float4 a1 = *reinterpret_cast<const float4*>(xp + 4);
  short8 af;
  af[0] = (short)f32_to_bf16(a0.x); af[1] = (short)f32_to_bf16(a0.y);
  af[2] = (short)f32_to_bf16(a0.z); af[3] = (short)f32_to_bf16(a0.w);
  af[4] = (short)f32_to_bf16(a1.x); af[5] = (short)f32_to_bf16(a1.y);
  af[6] = (short)f32_to_bf16(a1.z); af[7] = (short)f32_to_bf16(a1.w);
  for (int t = wave; t < 50; t += 4) {
    short8 bf = *reinterpret_cast<const short8*>(wbf + ((t * 4 + quad) * 16 + c16) * 8);
    float4v acc = {0.f, 0.f, 0.f, 0.f};
    acc = __builtin_amdgcn_mfma_f32_16x16x32_bf16(af, bf, acc, 0, 0, 0);
    int cg = t * 16 + c16;
#pragma unroll
    for (int r = 0; r < 4; r++) ot[(quad * 4 + r) * 800 + cg] = f32_to_bf16(acc[r]);
  }
  __syncthreads();
  const uint4* src = (const uint4*)ot;
  uint4* dst = (uint4*)(xw + (size_t)n0 * 800);
  for (int i = tid; i < 1600; i += 256) dst[i] = src[i];
}

// ---------------------------------------------------------------------------
// K2: one wave per target node; halves process alternate edges (lane=f_out).
// Decodes 8B packets (no index math in hot loop), 2-edge unroll per half.
// ---------------------------------------------------------------------------
__device__ __forceinline__ void edge_step(uint2 pk, const unsigned short* __restrict__ xwf,
                                          float a2, float rd, float& acc, float& den) {
  unsigned long long v = ((unsigned long long)pk.y << 32) | pk.x;
  int col = (int)(v & 0x1FFFF);
  int w0 = (int)((v >> 17) & 31), w1 = (int)((v >> 22) & 31);
  int w2 = (int)((v >> 27) & 31), w3 = (int)((v >> 32) & 31);
  float fr0 = (float)(unsigned int)((v >> 37) & 8191) * (1.f / 8191.f);
  float fr1 = (float)(unsigned int)((v >> 50) & 8191) * (1.f / 8191.f);
  const unsigned short* base = xwf + (size_t)col * 800;
  float g0 = bf16_to_f32(base[w0 * 32]);
  float g1 = bf16_to_f32(base[w1 * 32]);
  float g2 = bf16_to_f32(base[w2 * 32]);
  float g3 = bf16_to_f32(base[w3 * 32]);
  float c0 = 1.f - fr0, c1 = 1.f - fr1;
  float msg = c1 * (c0 * g0 + fr0 * g1) + fr1 * (c0 * g2 + fr0 * g3);
  float t = msg * a2;
#pragma unroll
  for (int m = 16; m >= 1; m >>= 1) t += __shfl_xor(t, m);
  float alpha = rd + t;
  alpha = alpha > 0.f ? alpha : 0.2f * alpha;
  float ex = __expf(alpha);
  acc += msg * ex;
  den += ex;
}

__global__ __launch_bounds__(256) void k2_csr(
    const int* __restrict__ offs, const uint2* __restrict__ epack,
    const unsigned short* __restrict__ xw, const float* __restrict__ r_dot,
    const float* __restrict__ att_w, float* __restrict__ out) {
  int tid = threadIdx.x;
  int wave = tid >> 6, lane = tid & 63;
  int node = blockIdx.x * 4 + wave;
  if (node >= N_NODES) return;
  int f = lane & 31, half = lane >> 5;
  float a2 = att_w[32 + f];
  float rd = r_dot[node];
  int s0 = offs[node], s1 = offs[node + 1];
  const unsigned short* xwf = xw + f;
  float acc = 0.f, den = 0.f;
  int i = s0 + half;
  for (; i + 2 < s1; i += 4) {
    uint2 pa = epack[i];
    uint2 pb = epack[i + 2];
    edge_step(pa, xwf, a2, rd, acc, den);
    edge_step(pb, xwf, a2, rd, acc, den);
  }
  for (; i < s1; i += 2) edge_step(epack[i], xwf, a2, rd, acc, den);
  acc += __shfl_xor(acc, 32);
  den += __shfl_xor(den, 32);
  if (half == 0) out[node * 32 + f] += acc / (den + 1e-16f);
}

extern "C" void kernel_launch(void* const* d_in, const int* in_sizes, int n_in,
                              void* d_out, int out_size, void* d_ws, size_t ws_size,
                              hipStream_t stream) {
  const float* x      = (const float*)d_in[0];
  const int*   ei     = (const int*)d_in[1];
  const float* pseudo = (const float*)d_in[2];
  const float* weight = (const float*)d_in[3];
  const float* root_w = (const float*)d_in[4];
  const float* att_w  = (const float*)d_in[5];
  const float* bias   = (const float*)d_in[6];
  float* out = (float*)d_out;

  char* ws = (char*)d_ws;
  unsigned short* xw  = (unsigned short*)ws;                 // 160,000,000 B
  float* r_dot        = (float*)(ws + 160000000);            //    400,000 B
  unsigned short* wbf = (unsigned short*)(ws + 160400000);   //     51,200 B
  int* deg            = (int*)(ws + 160451200);              //    400,000 B
  int* offs           = (int*)(ws + 160851200);              //    400,016 B
  unsigned long long* tilepack = (unsigned long long*)(ws + 161251216); // 3,128 B
  int* tilectr        = (int*)(ws + 161254344);              //          8 B
  int* cursor         = (int*)(ws + 161254352);              //    400,000 B
  uint2* epack        = (uint2*)(ws + 161654352);            // 12,800,000 B -> 174.5 MB

  hipLaunchKernelGGL(k_zero, dim3(NBLK_SCAN), dim3(256), 0, stream,
                     deg, tilepack, tilectr);
  hipLaunchKernelGGL(k_B, dim3(12500), dim3(256), 0, stream,
                     x, root_w, att_w, bias, ei, weight, out, r_dot, deg, wbf);
  hipLaunchKernelGGL(k_scan, dim3(NBLK_SCAN), dim3(256), 0, stream,
                     deg, offs, cursor, tilectr, tilepack);
  hipLaunchKernelGGL(k_C, dim3(12500), dim3(256), 0, stream,
                     ei, pseudo, cursor, epack, x, wbf, xw);
  hipLaunchKernelGGL(k2_csr, dim3(25000), dim3(256), 0, stream,
                     offs, epack, xw, r_dot, att_w, out);
}

// Round 5
// 336.843 us; speedup vs baseline: 1.4007x; 1.4007x over previous
//
#include <hip/hip_runtime.h>
#include <stdint.h>

#define N_NODES 100000
#define N_EDGES 1600000
#define NBLK_SCAN 391   // ceil(N_NODES/256)

typedef __attribute__((ext_vector_type(8))) short short8;
typedef __attribute__((ext_vector_type(4))) float float4v;

__device__ __forceinline__ unsigned short f32_to_bf16(float f) {
  uint32_t u = __float_as_uint(f);
  u += 0x7fffu + ((u >> 16) & 1u);   // RNE
  return (unsigned short)(u >> 16);
}
__device__ __forceinline__ float bf16_to_f32(unsigned short h) {
  return __uint_as_float(((uint32_t)h) << 16);
}

// ---------------------------------------------------------------------------
// K_zero: deg=0; swizzle weight (25 mats -> tiles 0..49) and root_w
// (tiles 50..51) into MFMA B-fragment bf16 order:
// wbf[((t*4+q)*16+c)*8+j], q=kk>>3, j=kk&7, c=fo&15.
// ---------------------------------------------------------------------------
__global__ __launch_bounds__(256) void k_zero(
    const float* __restrict__ weight, const float* __restrict__ root_w,
    int* __restrict__ deg, unsigned short* __restrict__ wbf) {
  int tid = threadIdx.x;
  int b = blockIdx.x;
  int i = b * 256 + tid;
  if (i < N_NODES) deg[i] = 0;
  if (b < 100) {            // 25600 weight elements
    int e = i;
    int km = e >> 10;
    int rem = e & 1023;
    int kk = rem >> 5;
    int fo = rem & 31;
    int t = km * 2 + (fo >> 4);
    int c = fo & 15;
    int q = kk >> 3, j = kk & 7;
    wbf[((t * 4 + q) * 16 + c) * 8 + j] = f32_to_bf16(weight[e]);
  } else if (b == 100) {    // 1024 root_w elements -> tiles 50,51
    for (int idx = tid; idx < 1024; idx += 256) {
      int kk = idx >> 5;
      int fo = idx & 31;
      int t = 50 + (fo >> 4);
      int c = fo & 15;
      int q = kk >> 3, j = kk & 7;
      wbf[((t * 4 + q) * 16 + c) * 8 + j] = f32_to_bf16(root_w[idx]);
    }
  }
}

// ---------------------------------------------------------------------------
// K1 (6250 blocks, 16 nodes each; 6250*256 == N_EDGES exactly):
//  - hist: rank[e] = atomicAdd(&deg[ei[e]],1)  (1 edge/thread, latency hidden)
//  - xw[n][km*32+fo] = (x @ W_km)[n][fo] bf16 via MFMA 16x16x32 (tiles 0..49),
//    LDS-staged (stride 808 to cut bank conflicts), coalesced uint4 store
//  - tiles 50,51 = x @ root_w: out = x_root + bias; r_dot = x_root . att_w[:32]
// ---------------------------------------------------------------------------
__global__ __launch_bounds__(256) void k1_xw(
    const float* __restrict__ x, const unsigned short* __restrict__ wbf,
    const int* __restrict__ ei, const float* __restrict__ att_w,
    const float* __restrict__ bias,
    int* __restrict__ deg, unsigned short* __restrict__ rank,
    unsigned short* __restrict__ xw, float* __restrict__ out,
    float* __restrict__ r_dot) {
  __shared__ __align__(16) unsigned short ot[16 * 808];
  __shared__ float xr[16][33];
  int tid = threadIdx.x;
  int b = blockIdx.x;

  // histogram + rank; store deferred to the end so the atomic overlaps MFMA
  int e = b * 256 + tid;
  int rk = atomicAdd(&deg[ei[e]], 1);

  int wave = tid >> 6, lane = tid & 63;
  int quad = lane >> 4, c16 = lane & 15;
  int n0 = b * 16;
  const float* xp = x + (size_t)(n0 + c16) * 32 + quad * 8;
  float4 a0 = *reinterpret_cast<const float4*>(xp);
  float4 a1 = *reinterpret_cast<const float4*>(xp + 4);
  short8 af;
  af[0] = (short)f32_to_bf16(a0.x); af[1] = (short)f32_to_bf16(a0.y);
  af[2] = (short)f32_to_bf16(a0.z); af[3] = (short)f32_to_bf16(a0.w);
  af[4] = (short)f32_to_bf16(a1.x); af[5] = (short)f32_to_bf16(a1.y);
  af[6] = (short)f32_to_bf16(a1.z); af[7] = (short)f32_to_bf16(a1.w);

  for (int t = wave; t < 52; t += 4) {
    short8 bf = *reinterpret_cast<const short8*>(wbf + ((t * 4 + quad) * 16 + c16) * 8);
    float4v acc = {0.f, 0.f, 0.f, 0.f};
    acc = __builtin_amdgcn_mfma_f32_16x16x32_bf16(af, bf, acc, 0, 0, 0);
    if (t < 50) {
      int cg = t * 16 + c16;
#pragma unroll
      for (int r = 0; r < 4; r++) ot[(quad * 4 + r) * 808 + cg] = f32_to_bf16(acc[r]);
    } else {
      int f = (t - 50) * 16 + c16;
#pragma unroll
      for (int r = 0; r < 4; r++) xr[quad * 4 + r][f] = acc[r];
    }
  }
  __syncthreads();

  // coalesced copy-out: ot rows (101 uint4 stride) -> xw rows (100 uint4)
  const uint4* src = (const uint4*)ot;
  uint4* dst = (uint4*)(xw + (size_t)n0 * 800);
  for (int i = tid; i < 1600; i += 256) {
    int r = i / 100;
    int c = i - r * 100;
    dst[r * 100 + c] = src[r * 101 + c];
  }
  // out = x_root + bias  (512 entries, 256 threads -> 2 iterations)
  for (int idx = tid; idx < 512; idx += 256) {
    int n = idx >> 5, f = idx & 31;
    out[(n0 + n) * 32 + f] = xr[n][f] + bias[f];
  }
  // r_dot
  if (tid < 16) {
    float s = 0.f;
#pragma unroll
    for (int f = 0; f < 32; f++) s += xr[tid][f] * att_w[f];
    r_dot[n0 + tid] = s;
  }
  rank[e] = (unsigned short)rk;
}

// ---------------------------------------------------------------------------
// 3-kernel exclusive scan of deg -> offs (known-fast from round 2).
// ---------------------------------------------------------------------------
__global__ __launch_bounds__(256) void kscan1(const int* __restrict__ deg,
                                              int* __restrict__ incl,
                                              int* __restrict__ bsum) {
  __shared__ int s[256];
  int tid = threadIdx.x;
  int i = blockIdx.x * 256 + tid;
  int v = (i < N_NODES) ? deg[i] : 0;
  s[tid] = v;
  __syncthreads();
  for (int d = 1; d < 256; d <<= 1) {
    int t = (tid >= d) ? s[tid - d] : 0;
    __syncthreads();
    s[tid] += t;
    __syncthreads();
  }
  if (i < N_NODES) incl[i] = s[tid];
  if (tid == 255) bsum[blockIdx.x] = s[255];
}

__global__ __launch_bounds__(512) void kscan2(const int* __restrict__ bsum,
                                              int* __restrict__ bbase) {
  __shared__ int s[512];
  int tid = threadIdx.x;
  int v = (tid < NBLK_SCAN) ? bsum[tid] : 0;
  s[tid] = v;
  __syncthreads();
  for (int d = 1; d < 512; d <<= 1) {
    int t = (tid >= d) ? s[tid - d] : 0;
    __syncthreads();
    s[tid] += t;
    __syncthreads();
  }
  if (tid < NBLK_SCAN) bbase[tid] = s[tid] - v;  // exclusive
}

__global__ __launch_bounds__(256) void kscan3(const int* __restrict__ deg,
                                              int* __restrict__ offs,
                                              const int* __restrict__ bbase) {
  int i = blockIdx.x * 256 + threadIdx.x;
  if (i < N_NODES) offs[i] = offs[i] - deg[i] + bbase[i >> 8];
  if (i == 0) offs[N_NODES] = N_EDGES;
}

// ---------------------------------------------------------------------------
// K_scatter: NO atomics — pos = offs[row] + rank[e]. 8 edges/thread for MLP.
// Packet: col(17b) | w0..w3(4x5b) | fr0,fr1(2x13b).
// ---------------------------------------------------------------------------
__global__ __launch_bounds__(256) void kscatter(
    const int* __restrict__ ei, const float* __restrict__ pseudo,
    const int* __restrict__ offs, const unsigned short* __restrict__ rank,
    uint2* __restrict__ epack) {
  int tid = threadIdx.x;
  int base = blockIdx.x * 2048;
#pragma unroll
  for (int k = 0; k < 8; k++) {
    int e = base + k * 256 + tid;
    if (e < N_EDGES) {
      int r = ei[e];
      int c = ei[N_EDGES + e];
      int pos = offs[r] + (int)rank[e];
      float p0 = pseudo[2 * e] * 4.f;
      float p1 = pseudo[2 * e + 1] * 4.f;
      float fl0 = floorf(p0), fl1 = floorf(p1);
      float fr0 = p0 - fl0, fr1 = p1 - fl1;
      int i0 = (int)fl0, i1 = (int)fl1;
      int a0 = min(i0, 4), a0p = min(i0 + 1, 4);
      int a1 = 5 * min(i1, 4), a1p = 5 * min(i1 + 1, 4);
      unsigned long long w0 = (unsigned long long)(a0 + a1);
      unsigned long long w1 = (unsigned long long)(a0p + a1);
      unsigned long long w2 = (unsigned long long)(a0 + a1p);
      unsigned long long w3 = (unsigned long long)(a0p + a1p);
      unsigned long long q0 = (unsigned long long)__float2uint_rn(fr0 * 8191.f);
      unsigned long long q1 = (unsigned long long)__float2uint_rn(fr1 * 8191.f);
      unsigned long long v = (unsigned long long)(unsigned int)c |
                             (w0 << 17) | (w1 << 22) | (w2 << 27) | (w3 << 32) |
                             (q0 << 37) | (q1 << 50);
      uint2 pk;
      pk.x = (unsigned int)v;
      pk.y = (unsigned int)(v >> 32);
      epack[pos] = pk;
    }
  }
}

// ---------------------------------------------------------------------------
// K2: one wave per node; halves process alternate edges (lane=f_out);
// 4-deep unroll per half (8 edges in flight/wave, 32 outstanding gathers).
// ---------------------------------------------------------------------------
__device__ __forceinline__ void decode_pk(uint2 pk, int& col, int& w0, int& w1,
                                          int& w2, int& w3, float& fr0, float& fr1) {
  unsigned long long v = ((unsigned long long)pk.y << 32) | pk.x;
  col = (int)(v & 0x1FFFF);
  w0 = (int)((v >> 17) & 31); w1 = (int)((v >> 22) & 31);
  w2 = (int)((v >> 27) & 31); w3 = (int)((v >> 32) & 31);
  fr0 = (float)(unsigned int)((v >> 37) & 8191) * (1.f / 8191.f);
  fr1 = (float)(unsigned int)((v >> 50) & 8191) * (1.f / 8191.f);
}

__device__ __forceinline__ void edge_step(uint2 pk, const unsigned short* __restrict__ xwf,
                                          float a2, float rd, float& acc, float& den) {
  int col, w0, w1, w2, w3; float fr0, fr1;
  decode_pk(pk, col, w0, w1, w2, w3, fr0, fr1);
  const unsigned short* base = xwf + (size_t)col * 800;
  float g0 = bf16_to_f32(base[w0 * 32]);
  float g1 = bf16_to_f32(base[w1 * 32]);
  float g2 = bf16_to_f32(base[w2 * 32]);
  float g3 = bf16_to_f32(base[w3 * 32]);
  float c0 = 1.f - fr0, c1 = 1.f - fr1;
  float msg = c1 * (c0 * g0 + fr0 * g1) + fr1 * (c0 * g2 + fr0 * g3);
  float t = msg * a2;
#pragma unroll
  for (int m = 16; m >= 1; m >>= 1) t += __shfl_xor(t, m);
  float alpha = rd + t;
  alpha = alpha > 0.f ? alpha : 0.2f * alpha;
  float ex = __expf(alpha);
  acc += msg * ex;
  den += ex;
}

__global__ __launch_bounds__(256) void k2_csr(
    const int* __restrict__ offs, const uint2* __restrict__ epack,
    const unsigned short* __restrict__ xw, const float* __restrict__ r_dot,
    const float* __restrict__ att_w, float* __restrict__ out) {
  int tid = threadIdx.x;
  int wave = tid >> 6, lane = tid & 63;
  int node = blockIdx.x * 4 + wave;
  if (node >= N_NODES) return;
  int f = lane & 31, half = lane >> 5;
  float a2 = att_w[32 + f];
  float rd = r_dot[node];
  int s0 = offs[node], s1 = offs[node + 1];
  const unsigned short* xwf = xw + f;
  float acc = 0.f, den = 0.f;
  int i = s0 + half;

  for (; i + 6 < s1; i += 8) {
    uint2 p[4];
    p[0] = epack[i];     p[1] = epack[i + 2];
    p[2] = epack[i + 4]; p[3] = epack[i + 6];
    int col[4], w0[4], w1[4], w2[4], w3[4];
    float fr0[4], fr1[4];
#pragma unroll
    for (int u = 0; u < 4; u++)
      decode_pk(p[u], col[u], w0[u], w1[u], w2[u], w3[u], fr0[u], fr1[u]);
    float g0[4], g1[4], g2[4], g3[4];
#pragma unroll
    for (int u = 0; u < 4; u++) {
      const unsigned short* base = xwf + (size_t)col[u] * 800;
      g0[u] = bf16_to_f32(base[w0[u] * 32]);
      g1[u] = bf16_to_f32(base[w1[u] * 32]);
      g2[u] = bf16_to_f32(base[w2[u] * 32]);
      g3[u] = bf16_to_f32(base[w3[u] * 32]);
    }
    float msg[4], t[4];
#pragma unroll
    for (int u = 0; u < 4; u++) {
      float c0 = 1.f - fr0[u], c1 = 1.f - fr1[u];
      msg[u] = c1 * (c0 * g0[u] + fr0[u] * g1[u]) + fr1[u] * (c0 * g2[u] + fr0[u] * g3[u]);
      t[u] = msg[u] * a2;
    }
#pragma unroll
    for (int m = 16; m >= 1; m >>= 1) {
      t[0] += __shfl_xor(t[0], m);
      t[1] += __shfl_xor(t[1], m);
      t[2] += __shfl_xor(t[2], m);
      t[3] += __shfl_xor(t[3], m);
    }
#pragma unroll
    for (int u = 0; u < 4; u++) {
      float alpha = rd + t[u];
      alpha = alpha > 0.f ? alpha : 0.2f * alpha;
      float ex = __expf(alpha);
      acc += msg[u] * ex;
      den += ex;
    }
  }
  for (; i < s1; i += 2) edge_step(epack[i], xwf, a2, rd, acc, den);

  acc += __shfl_xor(acc, 32);
  den += __shfl_xor(den, 32);
  if (half == 0) out[node * 32 + f] += acc / (den + 1e-16f);
}

extern "C" void kernel_launch(void* const* d_in, const int* in_sizes, int n_in,
                              void* d_out, int out_size, void* d_ws, size_t ws_size,
                              hipStream_t stream) {
  const float* x      = (const float*)d_in[0];
  const int*   ei     = (const int*)d_in[1];
  const float* pseudo = (const float*)d_in[2];
  const float* weight = (const float*)d_in[3];
  const float* root_w = (const float*)d_in[4];
  const float* att_w  = (const float*)d_in[5];
  const float* bias   = (const float*)d_in[6];
  float* out = (float*)d_out;

  char* ws = (char*)d_ws;
  unsigned short* xw   = (unsigned short*)ws;                 // 160,000,000 B
  float* r_dot         = (float*)(ws + 160000000);            //    400,000 B
  unsigned short* wbf  = (unsigned short*)(ws + 160400000);   //     53,248 B (52 tiles)
  int* deg             = (int*)(ws + 160453504);              //    400,000 B
  int* offs            = (int*)(ws + 160853504);              //    400,016 B
  int* bsum            = (int*)(ws + 161253520);              //      1,600 B
  int* bbase           = (int*)(ws + 161255120);              //      1,600 B
  unsigned short* rank = (unsigned short*)(ws + 161256720);   //  3,200,000 B
  uint2* epack         = (uint2*)(ws + 164456720);            // 12,800,000 B -> 177.3 MB

  hipLaunchKernelGGL(k_zero, dim3(NBLK_SCAN), dim3(256), 0, stream,
                     weight, root_w, deg, wbf);
  hipLaunchKernelGGL(k1_xw, dim3(6250), dim3(256), 0, stream,
                     x, wbf, ei, att_w, bias, deg, rank, xw, out, r_dot);
  hipLaunchKernelGGL(kscan1, dim3(NBLK_SCAN), dim3(256), 0, stream, deg, offs, bsum);
  hipLaunchKernelGGL(kscan2, dim3(1), dim3(512), 0, stream, bsum, bbase);
  hipLaunchKernelGGL(kscan3, dim3(NBLK_SCAN), dim3(256), 0, stream, deg, offs, bbase);
  hipLaunchKernelGGL(kscatter, dim3(782), dim3(256), 0, stream,
                     ei, pseudo, offs, rank, epack);
  hipLaunchKernelGGL(k2_csr, dim3(25000), dim3(256), 0, stream,
                     offs, epack, xw, r_dot, att_w, out);
}